// Round 1
// baseline (307.229 us; speedup 1.0000x reference)
//
#include <hip/hip_runtime.h>
#include <hip/hip_bf16.h>

// BlocDiagLinear: out[b, n*128+r] = sum_c x[b, n*128+c] * blocks[n, r, c]
// 64 GEMMs M=4096 N=128 K=128, fp32 I/O, bf16 MFMA.
// R4: latency/occupancy attack.
//  (1) LDS 34816->32768 B (drop pad, XOR swizzle instead) -> 5 WGs/CU (20 waves)
//      vs previous 3 WGs (12 waves). __launch_bounds__(256,5).
//  (2) Wave decomposition 2x2(r-half,batch-half) -> 4 batch quarters: each wave
//      computes all 128 r for its 32 batch rows. Kills the 2x duplicate x-loads
//      and halves fp32->bf16 convert VALU work. Same 64 MFMA + 64 ds_read/wave.
//  (3) All 16 float4 x-loads issued BEFORE W staging: 8 KB/wave in flight, x
//      latency hides under stage+barrier (FIFO vmcnt retirement => the ds_write
//      waits already imply x has retired; post-barrier loop never stalls on VMEM).

typedef __bf16 bf16_8 __attribute__((ext_vector_type(8)));
typedef __bf16 bf16_4 __attribute__((ext_vector_type(4)));
typedef float f32x4 __attribute__((ext_vector_type(4)));

__global__ __launch_bounds__(256, 5)
void BlocDiagLinear_kernel(const float* __restrict__ x,
                           const float* __restrict__ blocks,
                           float* __restrict__ out)
{
    __shared__ __align__(16) __bf16 ws[128 * 128];  // 32768 B, XOR-swizzled

    const int bid = blockIdx.x;
    const int nb  = bid & 63;   // block index — FAST index (channel balance)
    const int mt  = bid >> 6;   // batch tile 0..31

    const int t    = threadIdx.x;
    const int lane = t & 63;
    const int w    = t >> 6;      // batch quarter 0..3 (32 rows each)
    const int lm   = lane & 15;   // batch row within 16 (MFMA D-col)
    const int q    = lane >> 4;   // 8-col group within 32-wide K chunk

    // ---- issue ALL x loads first: independent of LDS, overlaps W staging ----
    const float* xb = x + (size_t)(mt * 128 + w * 32 + lm) * 8192
                        + (size_t)nb * 128 + q * 8;
    float4 raw[16];
#pragma unroll
    for (int ni = 0; ni < 2; ++ni)
#pragma unroll
        for (int kk = 0; kk < 4; ++kk) {
            const float* p = xb + (size_t)ni * 16 * 8192 + kk * 32;
            raw[ni * 8 + 2 * kk]     = *(const float4*)(p);
            raw[ni * 8 + 2 * kk + 1] = *(const float4*)(p + 4);
        }

    // ---- stage W block (128x128) fp32 -> bf16 into swizzled LDS ----
    // element (row,col) lives at byte (row*256 + col*2) ^ ((row&7)<<4)
    const int c4 = t & 31;
    const int r0 = t >> 5;        // == row & 7 below
    const float* wg = blocks + (size_t)nb * 16384;
    char* wsb = (char*)ws;
#pragma unroll
    for (int i = 0; i < 16; ++i) {
        const int row = i * 8 + r0;
        const float4 vw = *(const float4*)(wg + row * 128 + c4 * 4);
        bf16_4 bw = { (__bf16)vw.x, (__bf16)vw.y, (__bf16)vw.z, (__bf16)vw.w };
        *(bf16_4*)(wsb + ((row * 256 + c4 * 8) ^ (r0 << 4))) = bw;
    }
    __syncthreads();

    f32x4 acc[8][2];
#pragma unroll
    for (int mi = 0; mi < 8; ++mi)
#pragma unroll
        for (int ni = 0; ni < 2; ++ni)
            acc[mi][ni] = (f32x4){0.f, 0.f, 0.f, 0.f};

    const int swz = (lm & 7) << 4;   // (rr&7)<<4 — mi*16 doesn't change rr&7

#pragma unroll
    for (int ni = 0; ni < 2; ++ni) {
        bf16_8 b[4];
#pragma unroll
        for (int kk = 0; kk < 4; ++kk) {
            const float4 lo = raw[ni * 8 + 2 * kk];
            const float4 hi = raw[ni * 8 + 2 * kk + 1];
            b[kk] = (bf16_8){ (__bf16)lo.x, (__bf16)lo.y, (__bf16)lo.z, (__bf16)lo.w,
                              (__bf16)hi.x, (__bf16)hi.y, (__bf16)hi.z, (__bf16)hi.w };
        }
#pragma unroll
        for (int kk = 0; kk < 4; ++kk) {
            bf16_8 a[8];
#pragma unroll
            for (int mi = 0; mi < 8; ++mi) {
                const int byte = ((mi * 16 + lm) * 256 + kk * 64 + q * 16) ^ swz;
                a[mi] = *(const bf16_8*)(wsb + byte);
            }
#pragma unroll
            for (int mi = 0; mi < 8; ++mi)
                acc[mi][ni] = __builtin_amdgcn_mfma_f32_16x16x32_bf16(
                                  a[mi], b[kk], acc[mi][ni], 0, 0, 0);
        }
    }

    // Epilogue: D row = q*4+reg -> r (consecutive => float4 along r), col = lm -> batch.
    float* og = out + (size_t)(mt * 128 + w * 32 + lm) * 8192
                    + (size_t)nb * 128 + q * 4;
#pragma unroll
    for (int ni = 0; ni < 2; ++ni)
#pragma unroll
        for (int mi = 0; mi < 8; ++mi)
            *(f32x4*)(og + (size_t)ni * 16 * 8192 + mi * 16) = acc[mi][ni];
}

extern "C" void kernel_launch(void* const* d_in, const int* in_sizes, int n_in,
                              void* d_out, int out_size, void* d_ws, size_t ws_size,
                              hipStream_t stream) {
    const float* x      = (const float*)d_in[0];
    const float* blocks = (const float*)d_in[1];
    float* out          = (float*)d_out;
    BlocDiagLinear_kernel<<<dim3(64 * 32), dim3(256), 0, stream>>>(x, blocks, out);
}

// Round 2
// 234.254 us; speedup vs baseline: 1.3115x; 1.3115x over previous
//
#include <hip/hip_runtime.h>
#include <hip/hip_bf16.h>

// BlocDiagLinear: out[b, n*128+r] = sum_c x[b, n*128+c] * blocks[n, r, c]
// 64 GEMMs M=4096 N=128 K=128, fp32 I/O, bf16 MFMA.
// R5: R4's occupancy idea WITHOUT the spill.
//  R4 post-mortem: __launch_bounds__(256,5) forced the allocator to the
//  <=64-VGPR occupancy level (HW steps halve at 64/128/256) -> 48 VGPR,
//  raw[16]+acc[8][2] spilled to scratch: FETCH +117 MB, WRITE +221 MB.
//  Fix: 16 batch rows/wave (acc[8]=32 regs, raw[8]=32, b[4]=16) -> ~95 VGPR
//  peak, honest fit at the 128-VGPR / 4-waves-per-SIMD level.
//  512-thread WGs (8 waves x 16 rows = 128-row tile, grid unchanged 2048):
//  halves W-staging traffic vs 64-row/256-thread WGs; 2 WGs/CU = 16 waves.

typedef __bf16 bf16_8 __attribute__((ext_vector_type(8)));
typedef __bf16 bf16_4 __attribute__((ext_vector_type(4)));
typedef float f32x4 __attribute__((ext_vector_type(4)));

__global__ __launch_bounds__(512, 4)
void BlocDiagLinear_kernel(const float* __restrict__ x,
                           const float* __restrict__ blocks,
                           float* __restrict__ out)
{
    __shared__ __align__(16) __bf16 ws[128 * 128];  // 32768 B, XOR-swizzled

    const int bid = blockIdx.x;
    const int nb  = bid & 63;   // block index — FAST index (channel balance)
    const int mt  = bid >> 6;   // batch tile 0..31

    const int t    = threadIdx.x;
    const int lane = t & 63;
    const int w    = t >> 6;      // wave id 0..7 -> 16-row batch group
    const int lm   = lane & 15;   // batch row within 16 (MFMA D-col)
    const int q    = lane >> 4;   // 8-col group within 32-wide K chunk

    // ---- issue ALL x loads first: independent of LDS, overlap W staging ----
    const float* xb = x + (size_t)(mt * 128 + w * 16 + lm) * 8192
                        + (size_t)nb * 128 + q * 8;
    float4 raw[8];
#pragma unroll
    for (int kk = 0; kk < 4; ++kk) {
        raw[2 * kk]     = *(const float4*)(xb + kk * 32);
        raw[2 * kk + 1] = *(const float4*)(xb + kk * 32 + 4);
    }

    // ---- stage W block (128x128) fp32 -> bf16 into swizzled LDS ----
    // element (row,col) lives at byte (row*256 + col*2) ^ ((row&7)<<4)
    const int c4 = t & 31;        // col granule: 32 x 4 floats = 128 cols
    const int r0 = t >> 5;        // 0..15
    const float* wg = blocks + (size_t)nb * 16384;
    char* wsb = (char*)ws;
#pragma unroll
    for (int i = 0; i < 8; ++i) {
        const int row = i * 16 + r0;
        const float4 vw = *(const float4*)(wg + row * 128 + c4 * 4);
        bf16_4 bw = { (__bf16)vw.x, (__bf16)vw.y, (__bf16)vw.z, (__bf16)vw.w };
        *(bf16_4*)(wsb + ((row * 256 + c4 * 8) ^ ((r0 & 7) << 4))) = bw;
    }
    __syncthreads();

    // ---- convert x to bf16 B-fragments (raw dies here) ----
    bf16_8 b[4];
#pragma unroll
    for (int kk = 0; kk < 4; ++kk) {
        const float4 lo = raw[2 * kk];
        const float4 hi = raw[2 * kk + 1];
        b[kk] = (bf16_8){ (__bf16)lo.x, (__bf16)lo.y, (__bf16)lo.z, (__bf16)lo.w,
                          (__bf16)hi.x, (__bf16)hi.y, (__bf16)hi.z, (__bf16)hi.w };
    }

    f32x4 acc[8];
#pragma unroll
    for (int mi = 0; mi < 8; ++mi)
        acc[mi] = (f32x4){0.f, 0.f, 0.f, 0.f};

    const int swz = (lm & 7) << 4;   // mi*16 doesn't change row&7

#pragma unroll
    for (int kk = 0; kk < 4; ++kk) {
        bf16_8 a[8];
#pragma unroll
        for (int mi = 0; mi < 8; ++mi) {
            const int byte = ((mi * 16 + lm) * 256 + kk * 64 + q * 16) ^ swz;
            a[mi] = *(const bf16_8*)(wsb + byte);
        }
#pragma unroll
        for (int mi = 0; mi < 8; ++mi)
            acc[mi] = __builtin_amdgcn_mfma_f32_16x16x32_bf16(
                          a[mi], b[kk], acc[mi], 0, 0, 0);
    }

    // Epilogue: D row = q*4+reg -> r (consecutive => float4 along r), col = lm.
    float* og = out + (size_t)(mt * 128 + w * 16 + lm) * 8192
                    + (size_t)nb * 128 + q * 4;
#pragma unroll
    for (int mi = 0; mi < 8; ++mi)
        *(f32x4*)(og + mi * 16) = acc[mi];
}

extern "C" void kernel_launch(void* const* d_in, const int* in_sizes, int n_in,
                              void* d_out, int out_size, void* d_ws, size_t ws_size,
                              hipStream_t stream) {
    const float* x      = (const float*)d_in[0];
    const float* blocks = (const float*)d_in[1];
    float* out          = (float*)d_out;
    BlocDiagLinear_kernel<<<dim3(64 * 32), dim3(512), 0, stream>>>(x, blocks, out);
}